// Round 1
// baseline (800.707 us; speedup 1.0000x reference)
//
#include <hip/hip_runtime.h>
#include <hip/hip_bf16.h>
#include <math.h>

#define D_MODEL 1024
#define N_HEAD 16
#define HEAD 64
#define SEQ 2048
#define BATCH 4
#define ROWS (BATCH*SEQ)
#define FFD 4096

typedef __bf16 bf16;
typedef __attribute__((ext_vector_type(8))) __bf16 bf16x8;
typedef __attribute__((ext_vector_type(4))) __bf16 bf16x4;
typedef __attribute__((ext_vector_type(4))) float f32x4;

static_assert(sizeof(bf16x8) == 16, "bf16x8 must be 16B");

__device__ __forceinline__ void async_copy16(const void* g, void* l) {
  __builtin_amdgcn_global_load_lds((const __attribute__((address_space(1))) void*)g,
                                   (__attribute__((address_space(3))) void*)l, 16, 0, 0);
}

__device__ __forceinline__ f32x4 mfma16(bf16x8 a, bf16x8 b, f32x4 c) {
  return __builtin_amdgcn_mfma_f32_16x16x32_bf16(a, b, c, 0, 0, 0);
}

// ---------------- weight transpose + cast: in fp32 [R][C] -> out bf16 [C][R] ----------------
__global__ __launch_bounds__(256) void transpose_cast_kernel(const float* __restrict__ in,
                                                             bf16* __restrict__ out,
                                                             int R, int C) {
  __shared__ float ts[32][33];
  const int r0 = blockIdx.y * 32, c0 = blockIdx.x * 32;
  const int t = threadIdx.x, lr = t >> 3, lc = (t & 7) * 4;
  const float4 v = *(const float4*)(in + (size_t)(r0 + lr) * C + c0 + lc);
  ts[lr][lc + 0] = v.x; ts[lr][lc + 1] = v.y; ts[lr][lc + 2] = v.z; ts[lr][lc + 3] = v.w;
  __syncthreads();
  bf16x4 o;
  o[0] = (bf16)ts[lc + 0][lr]; o[1] = (bf16)ts[lc + 1][lr];
  o[2] = (bf16)ts[lc + 2][lr]; o[3] = (bf16)ts[lc + 3][lr];
  *(bf16x4*)(out + (size_t)(c0 + lr) * R + r0 + lc) = o;
}

// Wq/Wk/Wv [H][C][hs] fp32 -> out bf16 [3][N=H*hs][K=C]  (B^T layout for the QKV GEMM)
__global__ __launch_bounds__(256) void qkv_transpose_kernel(const float* __restrict__ Wq,
                                                            const float* __restrict__ Wk,
                                                            const float* __restrict__ Wv,
                                                            bf16* __restrict__ out) {
  __shared__ float ts[32][33];
  const int mat = blockIdx.z / N_HEAD, h = blockIdx.z % N_HEAD;
  const float* W = (mat == 0 ? Wq : mat == 1 ? Wk : Wv) + (size_t)h * D_MODEL * HEAD;
  bf16* o = out + (size_t)mat * D_MODEL * D_MODEL + (size_t)(h * HEAD) * D_MODEL;
  const int c0 = blockIdx.x * 32, s0 = blockIdx.y * 32;
  const int t = threadIdx.x, lr = t >> 3, lc = (t & 7) * 4;
  const float4 v = *(const float4*)(W + (size_t)(c0 + lr) * HEAD + s0 + lc);
  ts[lr][lc + 0] = v.x; ts[lr][lc + 1] = v.y; ts[lr][lc + 2] = v.z; ts[lr][lc + 3] = v.w;
  __syncthreads();
  bf16x4 ov;
  ov[0] = (bf16)ts[lc + 0][lr]; ov[1] = (bf16)ts[lc + 1][lr];
  ov[2] = (bf16)ts[lc + 2][lr]; ov[3] = (bf16)ts[lc + 3][lr];
  *(bf16x4*)(o + (size_t)(s0 + lr) * D_MODEL + c0 + lc) = ov;
}

// ---------------- LayerNorm: fp32 in -> bf16 out, one block per row ----------------
__global__ __launch_bounds__(256) void ln_kernel(const float* __restrict__ x,
                                                 const float* __restrict__ g,
                                                 const float* __restrict__ b,
                                                 bf16* __restrict__ h) {
  const int row = blockIdx.x, t = threadIdx.x;
  const float4 v = *(const float4*)(x + (size_t)row * D_MODEL + t * 4);
  float s = v.x + v.y + v.z + v.w;
  float ss = v.x * v.x + v.y * v.y + v.z * v.z + v.w * v.w;
#pragma unroll
  for (int m = 1; m < 64; m <<= 1) { s += __shfl_xor(s, m); ss += __shfl_xor(ss, m); }
  __shared__ float red[8];
  const int wave = t >> 6, lane = t & 63;
  if (lane == 0) { red[wave] = s; red[4 + wave] = ss; }
  __syncthreads();
  s = red[0] + red[1] + red[2] + red[3];
  ss = red[4] + red[5] + red[6] + red[7];
  const float mu = s * (1.f / D_MODEL);
  const float rstd = rsqrtf(ss * (1.f / D_MODEL) - mu * mu + 1e-5f);
  const float4 gv = *(const float4*)(g + t * 4);
  const float4 bv = *(const float4*)(b + t * 4);
  bf16x4 o;
  o[0] = (bf16)((v.x - mu) * rstd * gv.x + bv.x);
  o[1] = (bf16)((v.y - mu) * rstd * gv.y + bv.y);
  o[2] = (bf16)((v.z - mu) * rstd * gv.z + bv.z);
  o[3] = (bf16)((v.w - mu) * rstd * gv.w + bv.w);
  *(bf16x4*)(h + (size_t)row * D_MODEL + t * 4) = o;
}

// ---------------- GEMM: C[M][N] = A[M][K](bf16 rm) x Bt[N][K](bf16 rm), m97 structure ----------------
// EPI 0: scatter q/k as [B,H,T,hs], v as [B,H,hs,T] (all bf16)
// EPI 1: out fp32 = acc + bias[n] + resid[m*N+n]
// EPI 2: out bf16 = gelu(acc + bias[n])
// EPI 3: out fp32 = acc + bias[n] + resid[m*N+n]
template <int EPI>
__global__ __launch_bounds__(256) void gemm_kernel(const bf16* __restrict__ A,
                                                   const bf16* __restrict__ Bt, int K,
                                                   void* __restrict__ outp,
                                                   const float* __restrict__ bias,
                                                   const float* __restrict__ resid,
                                                   bf16* __restrict__ q_out,
                                                   bf16* __restrict__ k_out,
                                                   bf16* __restrict__ vt_out, int N) {
  __shared__ bf16 As[128 * 32];
  __shared__ bf16 Bs[128 * 32];
  const int t = threadIdx.x;
  const int bm = blockIdx.y, bn = blockIdx.x;
  const bf16* Ag = A + (size_t)(bm * 128 + (t >> 2)) * K + (t & 3) * 8;
  const bf16* Bg = Bt + (size_t)(bn * 128 + (t >> 2)) * K + (t & 3) * 8;
  bf16* Asw = As + t * 8;
  bf16* Bsw = Bs + t * 8;
  const int wave = t >> 6, lane = t & 63, l15 = lane & 15, l4 = lane >> 4;
  const int wm = (wave >> 1) * 64, wn = (wave & 1) * 64;
  const bf16* Ar = As + (wm + l15) * 32 + l4 * 8;
  const bf16* Br = Bs + (wn + l15) * 32 + l4 * 8;
  f32x4 acc[4][4];
#pragma unroll
  for (int i = 0; i < 4; i++)
#pragma unroll
    for (int j = 0; j < 4; j++) { f32x4 z = {0.f, 0.f, 0.f, 0.f}; acc[i][j] = z; }

  for (int kt = 0; kt < K; kt += 32) {
    __syncthreads();
    async_copy16(Ag + kt, Asw);
    async_copy16(Ag + kt + (size_t)64 * K, Asw + 2048);
    async_copy16(Bg + kt, Bsw);
    async_copy16(Bg + kt + (size_t)64 * K, Bsw + 2048);
    __syncthreads();
    bf16x8 af[4], bfr[4];
#pragma unroll
    for (int i = 0; i < 4; i++) af[i] = *(const bf16x8*)(Ar + i * 16 * 32);
#pragma unroll
    for (int j = 0; j < 4; j++) bfr[j] = *(const bf16x8*)(Br + j * 16 * 32);
#pragma unroll
    for (int i = 0; i < 4; i++)
#pragma unroll
      for (int j = 0; j < 4; j++) acc[i][j] = mfma16(af[i], bfr[j], acc[i][j]);
  }

#pragma unroll
  for (int i = 0; i < 4; i++) {
#pragma unroll
    for (int j = 0; j < 4; j++) {
      const int n = bn * 128 + wn + j * 16 + l15;
#pragma unroll
      for (int r = 0; r < 4; r++) {
        const int m = bm * 128 + wm + i * 16 + l4 * 4 + r;
        float val = acc[i][j][r];
        if constexpr (EPI == 0) {
          const int b = m >> 11, tt = m & 2047;
          if (n < D_MODEL) {
            const int hh = n >> 6, sgl = n & 63;
            q_out[(size_t)((b * N_HEAD + hh) * SEQ + tt) * HEAD + sgl] = (bf16)val;
          } else if (n < 2 * D_MODEL) {
            const int n2 = n - D_MODEL, hh = n2 >> 6, sgl = n2 & 63;
            k_out[(size_t)((b * N_HEAD + hh) * SEQ + tt) * HEAD + sgl] = (bf16)val;
          } else {
            const int n2 = n - 2 * D_MODEL, hh = n2 >> 6, sgl = n2 & 63;
            vt_out[(size_t)((b * N_HEAD + hh) * HEAD + sgl) * SEQ + tt] = (bf16)val;
          }
        } else if constexpr (EPI == 1) {
          ((float*)outp)[(size_t)m * N + n] = val + bias[n] + resid[(size_t)m * N + n];
        } else if constexpr (EPI == 2) {
          const float xg = val + bias[n];
          const float ge = 0.5f * xg * (1.f + erff(xg * 0.70710678118f));
          ((bf16*)outp)[(size_t)m * N + n] = (bf16)ge;
        } else {
          ((float*)outp)[(size_t)m * N + n] = val + bias[n] + resid[(size_t)m * N + n];
        }
      }
    }
  }
}

// ---------------- flash-style attention ----------------
// grid: B*H*(SEQ/64) blocks, 256 threads; wave w owns 16 q-rows; online softmax in regs.
__global__ __launch_bounds__(256) void attn_kernel(const bf16* __restrict__ q,
                                                   const bf16* __restrict__ k,
                                                   const bf16* __restrict__ vt,
                                                   bf16* __restrict__ att) {
  __shared__ bf16 Ks[64 * 64];
  __shared__ bf16 Vs[64 * 64];
  __shared__ bf16 Ps[4][16 * 64];
  const int t = threadIdx.x, wave = t >> 6, lane = t & 63;
  const int l15 = lane & 15, l4 = lane >> 4;
  const int bh = blockIdx.x >> 5, qt = blockIdx.x & 31;
  const bf16* qb = q + (size_t)bh * SEQ * HEAD;
  const bf16* kb = k + (size_t)bh * SEQ * HEAD;
  const bf16* vb = vt + (size_t)bh * HEAD * SEQ;
  const int qrow = qt * 64 + wave * 16;  // within sequence
  const bf16x8 qf0 = *(const bf16x8*)(qb + (size_t)(qrow + l15) * HEAD + l4 * 8);
  const bf16x8 qf1 = *(const bf16x8*)(qb + (size_t)(qrow + l15) * HEAD + 32 + l4 * 8);
  f32x4 o[4];
  float mrun[4], lrun[4];
#pragma unroll
  for (int r = 0; r < 4; r++) { f32x4 z = {0.f, 0.f, 0.f, 0.f}; o[r] = z; mrun[r] = -3e38f; lrun[r] = 0.f; }

  for (int u0 = 0; u0 < SEQ; u0 += 64) {
    __syncthreads();
    async_copy16(kb + (size_t)(u0 + (t >> 3)) * HEAD + (t & 7) * 8, &Ks[t * 8]);
    async_copy16(kb + (size_t)(u0 + (t >> 3) + 32) * HEAD + (t & 7) * 8, &Ks[t * 8 + 2048]);
    async_copy16(vb + (size_t)(t >> 3) * SEQ + u0 + (t & 7) * 8, &Vs[t * 8]);
    async_copy16(vb + (size_t)((t >> 3) + 32) * SEQ + u0 + (t & 7) * 8, &Vs[t * 8 + 2048]);
    __syncthreads();

    f32x4 sf[4];
#pragma unroll
    for (int n = 0; n < 4; n++) {
      const bf16x8 b0 = *(const bf16x8*)(&Ks[(n * 16 + l15) * 64 + l4 * 8]);
      const bf16x8 b1 = *(const bf16x8*)(&Ks[(n * 16 + l15) * 64 + 32 + l4 * 8]);
      f32x4 c = {0.f, 0.f, 0.f, 0.f};
      c = mfma16(qf0, b0, c);
      c = mfma16(qf1, b1, c);
      sf[n] = c;
    }
    float mloc[4] = {-3e38f, -3e38f, -3e38f, -3e38f};
#pragma unroll
    for (int n = 0; n < 4; n++) {
      const int ucol = u0 + n * 16 + l15;
#pragma unroll
      for (int r = 0; r < 4; r++) {
        float sv = sf[n][r] * 0.125f;
        if (qrow + l4 * 4 + r == ucol) sv = 0.f;  // diagonal score := 0 (pre-softmax)
        sf[n][r] = sv;
        mloc[r] = fmaxf(mloc[r], sv);
      }
    }
#pragma unroll
    for (int r = 0; r < 4; r++) {
      float mv = mloc[r];
#pragma unroll
      for (int mm = 1; mm < 16; mm <<= 1) mv = fmaxf(mv, __shfl_xor(mv, mm));
      const float mn = fmaxf(mrun[r], mv);
      const float al = __expf(mrun[r] - mn);
      mrun[r] = mn;
      lrun[r] *= al;
#pragma unroll
      for (int n2 = 0; n2 < 4; n2++) o[n2][r] *= al;
    }
    float lloc[4] = {0.f, 0.f, 0.f, 0.f};
#pragma unroll
    for (int n = 0; n < 4; n++)
#pragma unroll
      for (int r = 0; r < 4; r++) {
        const float p = __expf(sf[n][r] - mrun[r]);
        sf[n][r] = p;
        lloc[r] += p;
      }
#pragma unroll
    for (int r = 0; r < 4; r++) {
      float lv = lloc[r];
#pragma unroll
      for (int mm = 1; mm < 16; mm <<= 1) lv += __shfl_xor(lv, mm);
      lrun[r] += lv;
    }
    bf16* pw = &Ps[wave][0];
#pragma unroll
    for (int n = 0; n < 4; n++)
#pragma unroll
      for (int r = 0; r < 4; r++)
        pw[(l4 * 4 + r) * 64 + n * 16 + l15] = (bf16)sf[n][r];
    asm volatile("s_waitcnt lgkmcnt(0)" ::: "memory");
    const bf16x8 pa0 = *(const bf16x8*)(pw + l15 * 64 + l4 * 8);
    const bf16x8 pa1 = *(const bf16x8*)(pw + l15 * 64 + 32 + l4 * 8);
#pragma unroll
    for (int n2 = 0; n2 < 4; n2++) {
      const bf16x8 v0 = *(const bf16x8*)(&Vs[(n2 * 16 + l15) * 64 + l4 * 8]);
      const bf16x8 v1 = *(const bf16x8*)(&Vs[(n2 * 16 + l15) * 64 + 32 + l4 * 8]);
      o[n2] = mfma16(pa0, v0, o[n2]);
      o[n2] = mfma16(pa1, v1, o[n2]);
    }
  }
  const int b = bh >> 4, hh = bh & 15;
  float linv[4];
#pragma unroll
  for (int r = 0; r < 4; r++) linv[r] = 1.f / lrun[r];
#pragma unroll
  for (int n2 = 0; n2 < 4; n2++)
#pragma unroll
    for (int r = 0; r < 4; r++) {
      const int grow = b * SEQ + qrow + l4 * 4 + r;
      const int col = hh * HEAD + n2 * 16 + l15;
      att[(size_t)grow * D_MODEL + col] = (bf16)(o[n2][r] * linv[r]);
    }
}

extern "C" void kernel_launch(void* const* d_in, const int* in_sizes, int n_in,
                              void* d_out, int out_size, void* d_ws, size_t ws_size,
                              hipStream_t stream) {
  const float* x   = (const float*)d_in[0];
  const float* Wq  = (const float*)d_in[1];
  const float* Wk  = (const float*)d_in[2];
  const float* Wv  = (const float*)d_in[3];
  const float* Wo  = (const float*)d_in[4];
  const float* bo  = (const float*)d_in[5];
  const float* W1  = (const float*)d_in[6];
  const float* b1  = (const float*)d_in[7];
  const float* W2  = (const float*)d_in[8];
  const float* b2  = (const float*)d_in[9];
  const float* g1  = (const float*)d_in[10];
  const float* be1 = (const float*)d_in[11];
  const float* g2  = (const float*)d_in[12];
  const float* be2 = (const float*)d_in[13];
  float* out = (float*)d_out;

  // workspace layout (152 MB total)
  bf16* Wqkv_t = (bf16*)d_ws;                                  // [3][1024][1024]
  bf16* Wo_t   = Wqkv_t + (size_t)3 * D_MODEL * D_MODEL;       // [1024][1024]
  bf16* W1_t   = Wo_t + (size_t)D_MODEL * D_MODEL;             // [4096][1024]
  bf16* W2_t   = W1_t + (size_t)FFD * D_MODEL;                 // [1024][4096]
  bf16* hbuf   = W2_t + (size_t)D_MODEL * FFD;                 // [8192][1024] (h, later h2)
  float* x1    = (float*)(hbuf + (size_t)ROWS * D_MODEL);      // [8192][1024] fp32
  bf16* big    = (bf16*)(x1 + (size_t)ROWS * D_MODEL);         // qkv (50MB) then ff (64MB)
  bf16* qbuf   = big;
  bf16* kbuf   = qbuf + (size_t)ROWS * D_MODEL;
  bf16* vtbuf  = kbuf + (size_t)ROWS * D_MODEL;
  bf16* ffbuf  = big;                                          // reuse after attention
  bf16* attb   = big + (size_t)ROWS * FFD;                     // [8192][1024]

  qkv_transpose_kernel<<<dim3(D_MODEL / 32, HEAD / 32, 3 * N_HEAD), 256, 0, stream>>>(Wq, Wk, Wv, Wqkv_t);
  transpose_cast_kernel<<<dim3(D_MODEL / 32, D_MODEL / 32), 256, 0, stream>>>(Wo, Wo_t, D_MODEL, D_MODEL);
  transpose_cast_kernel<<<dim3(FFD / 32, D_MODEL / 32), 256, 0, stream>>>(W1, W1_t, D_MODEL, FFD);
  transpose_cast_kernel<<<dim3(D_MODEL / 32, FFD / 32), 256, 0, stream>>>(W2, W2_t, FFD, D_MODEL);
  ln_kernel<<<ROWS, 256, 0, stream>>>(x, g1, be1, hbuf);
  gemm_kernel<0><<<dim3(3 * D_MODEL / 128, ROWS / 128), 256, 0, stream>>>(
      hbuf, Wqkv_t, D_MODEL, nullptr, nullptr, nullptr, qbuf, kbuf, vtbuf, 3 * D_MODEL);
  attn_kernel<<<BATCH * N_HEAD * (SEQ / 64), 256, 0, stream>>>(qbuf, kbuf, vtbuf, attb);
  gemm_kernel<1><<<dim3(D_MODEL / 128, ROWS / 128), 256, 0, stream>>>(
      attb, Wo_t, D_MODEL, x1, bo, x, nullptr, nullptr, nullptr, D_MODEL);
  ln_kernel<<<ROWS, 256, 0, stream>>>(x1, g2, be2, hbuf);
  gemm_kernel<2><<<dim3(FFD / 128, ROWS / 128), 256, 0, stream>>>(
      hbuf, W1_t, D_MODEL, ffbuf, b1, nullptr, nullptr, nullptr, nullptr, FFD);
  gemm_kernel<3><<<dim3(D_MODEL / 128, ROWS / 128), 256, 0, stream>>>(
      ffbuf, W2_t, FFD, out, b2, x1, nullptr, nullptr, nullptr, D_MODEL);
}